// Round 1
// baseline (423.509 us; speedup 1.0000x reference)
//
#include <hip/hip_runtime.h>
#include <hip/hip_bf16.h>
#include <math.h>

#define N_TOT 1024
#define C_DIM 4096
#define NEGV  -1e30f

// ---------------------------------------------------------------------------
// zero the norm accumulators (2 * 1024 floats)
__global__ __launch_bounds__(256) void zero_kernel(float* __restrict__ p) {
    int t = threadIdx.x;
    #pragma unroll
    for (int s = 0; s < 8; s++) p[t + s * 256] = 0.0f;
}

// ---------------------------------------------------------------------------
// norms: normP[n] = sum_c G[c*N+n]^2 ; normK likewise. grid (4, 32), block 256
__global__ __launch_bounds__(256) void norms_kernel(const float* __restrict__ G,
                                                    const float* __restrict__ Kn,
                                                    float* __restrict__ normP,
                                                    float* __restrict__ normK) {
    int n  = blockIdx.x * 256 + threadIdx.x;
    int c0 = blockIdx.y * 128;
    float sp = 0.0f, sk = 0.0f;
    for (int c = c0; c < c0 + 128; c++) {
        float g = G[c * N_TOT + n];
        float k = Kn[c * N_TOT + n];
        sp = fmaf(g, g, sp);
        sk = fmaf(k, k, sk);
    }
    atomicAdd(&normP[n], sp);
    atomicAdd(&normK[n], sk);
}

// ---------------------------------------------------------------------------
// cosine GEMM: z=0 -> cos0 = (P . Kp^T)/norms, columns with flag!=0 -> NEG
//              z=1 -> cos1 = (P . P^T )/norms, columns with flag!=1 -> NEG
// A[i][k] = G[k*N + i] (reduction dim is the slow axis -> coalesced loads)
// 64x64 tile, BK=16, 256 threads, 4x4 micro-tile.
__global__ __launch_bounds__(256) void gemm_cos(const float* __restrict__ G,
                                                const float* __restrict__ Kn,
                                                const float* __restrict__ normP,
                                                const float* __restrict__ normK,
                                                const float* __restrict__ flag,
                                                float* __restrict__ cos0,
                                                float* __restrict__ cos1) {
    const int z = blockIdx.z;
    const float* A = G;
    const float* B = z ? G : Kn;
    const float* nB = z ? normP : normK;
    float* out = z ? cos1 : cos0;

    __shared__ float As[16][64];
    __shared__ float Bs[16][64];

    const int t  = threadIdx.x;
    const int tx = t & 15, ty = t >> 4;
    const int ib = blockIdx.x * 64, jb = blockIdx.y * 64;

    float acc[4][4] = {};

    for (int k0 = 0; k0 < C_DIM; k0 += 16) {
        #pragma unroll
        for (int s = 0; s < 4; s++) {
            int e   = t + s * 256;
            int kk  = e >> 6;
            int col = e & 63;
            As[kk][col] = A[(k0 + kk) * N_TOT + ib + col];
            Bs[kk][col] = B[(k0 + kk) * N_TOT + jb + col];
        }
        __syncthreads();
        #pragma unroll
        for (int kk = 0; kk < 16; kk++) {
            float4 av = *(const float4*)&As[kk][ty * 4];
            float4 bv = *(const float4*)&Bs[kk][tx * 4];
            float a[4] = {av.x, av.y, av.z, av.w};
            float b[4] = {bv.x, bv.y, bv.z, bv.w};
            #pragma unroll
            for (int ii = 0; ii < 4; ii++)
                #pragma unroll
                for (int jj = 0; jj < 4; jj++)
                    acc[ii][jj] = fmaf(a[ii], b[jj], acc[ii][jj]);
        }
        __syncthreads();
    }

    #pragma unroll
    for (int ii = 0; ii < 4; ii++) {
        int i = ib + ty * 4 + ii;
        float ni = normP[i];
        #pragma unroll
        for (int jj = 0; jj < 4; jj++) {
            int j = jb + tx * 4 + jj;
            float v = acc[ii][jj] / sqrtf(ni * nB[j]);
            float f = flag[j];
            bool keep = z ? (f == 1.0f) : (f == 0.0f);
            out[i * N_TOT + j] = keep ? v : NEGV;
        }
    }
}

// ---------------------------------------------------------------------------
// per-row top-2 (values + global indices), tie-break: lower index first.
// one wave per (row, matrix). grid (1024, 2), block 64.
__global__ __launch_bounds__(64) void topk_kernel(const float* __restrict__ cos0,
                                                  const float* __restrict__ cos1,
                                                  float* __restrict__ w01,   // [2][N][2]
                                                  int* __restrict__ i01) {   // [2][N][2]
    const int row = blockIdx.x;
    const int z   = blockIdx.y;
    const float* M = z ? cos1 : cos0;
    const int lane = threadIdx.x;

    float v1 = -INFINITY, v2 = -INFINITY;
    int   j1 = -1, j2 = -1;

    for (int s = 0; s < 16; s++) {
        int j = s * 64 + lane;
        float v = M[row * N_TOT + j];
        if (v > v1 || (v == v1 && j < j1)) {
            v2 = v1; j2 = j1; v1 = v; j1 = j;
        } else if (v > v2 || (v == v2 && j < j2)) {
            v2 = v; j2 = j;
        }
    }

    for (int off = 32; off > 0; off >>= 1) {
        float ov1 = __shfl_down(v1, off);
        float ov2 = __shfl_down(v2, off);
        int   oj1 = __shfl_down(j1, off);
        int   oj2 = __shfl_down(j2, off);
        bool b1 = (ov1 > v1) || (ov1 == v1 && oj1 < j1);
        if (b1) {
            bool b2 = (v1 > ov2) || (v1 == ov2 && j1 < oj2);
            float nv2 = b2 ? v1 : ov2;
            int   nj2 = b2 ? j1 : oj2;
            v1 = ov1; j1 = oj1; v2 = nv2; j2 = nj2;
        } else {
            bool b2 = (ov1 > v2) || (ov1 == v2 && oj1 < j2);
            if (b2) { v2 = ov1; j2 = oj1; }
        }
    }

    if (lane == 0) {
        int base = (z * N_TOT + row) * 2;
        w01[base]     = v1;
        w01[base + 1] = v2;
        i01[base]     = j1;
        i01[base + 1] = j2;
    }
}

// ---------------------------------------------------------------------------
// masked means of the 4 weight columns -> softmax -> weights[4]. one block.
__global__ __launch_bounds__(256) void means_kernel(const float* __restrict__ flag,
                                                    const float* __restrict__ w01,
                                                    float* __restrict__ weights) {
    __shared__ float sd[5][256];
    const int t = threadIdx.x;
    float nm = 0.0f, s0 = 0.0f, s1 = 0.0f, s2 = 0.0f, s3 = 0.0f;
    for (int n = t; n < N_TOT; n += 256) {
        float m = flag[n];
        nm += m;
        s0 += m * w01[n * 2 + 0];
        s1 += m * w01[n * 2 + 1];
        s2 += m * w01[2 * N_TOT + n * 2 + 0];
        s3 += m * w01[2 * N_TOT + n * 2 + 1];
    }
    sd[0][t] = nm; sd[1][t] = s0; sd[2][t] = s1; sd[3][t] = s2; sd[4][t] = s3;
    __syncthreads();
    for (int off = 128; off > 0; off >>= 1) {
        if (t < off) {
            #pragma unroll
            for (int q = 0; q < 5; q++) sd[q][t] += sd[q][t + off];
        }
        __syncthreads();
    }
    if (t == 0) {
        float inv = 1.0f / sd[0][0];
        float mv[4] = {sd[1][0] * inv, sd[2][0] * inv, sd[3][0] * inv, sd[4][0] * inv};
        float mx = fmaxf(fmaxf(mv[0], mv[1]), fmaxf(mv[2], mv[3]));
        float e[4], tot = 0.0f;
        #pragma unroll
        for (int q = 0; q < 4; q++) { e[q] = expf(mv[q] - mx); tot += e[q]; }
        #pragma unroll
        for (int q = 0; q < 4; q++) weights[q] = e[q] / tot;
    }
}

// ---------------------------------------------------------------------------
// output: copy generated & known, build rtn = sum_i w_i * gather_i.
// grid (4, 4096), block 256. thread -> (n, c). out[rtn] at 2CN + c*N + n.
__global__ __launch_bounds__(256) void output_kernel(const float* __restrict__ G,
                                                     const float* __restrict__ Kn,
                                                     const float* __restrict__ flag,
                                                     const int* __restrict__ i01,
                                                     const float* __restrict__ weights,
                                                     float* __restrict__ out) {
    const int n = blockIdx.x * 256 + threadIdx.x;
    const int c = blockIdx.y;

    float g = G[c * N_TOT + n];
    float k = Kn[c * N_TOT + n];
    out[c * N_TOT + n] = g;
    out[C_DIM * N_TOT + c * N_TOT + n] = k;

    const float w0 = weights[0], w1 = weights[1], w2 = weights[2], w3 = weights[3];

    float val = 0.0f;
    if (flag[n] == 1.0f) {
        int c00 = i01[n * 2 + 0];
        int c01 = i01[n * 2 + 1];
        int c10 = i01[2 * N_TOT + n * 2 + 0];
        int c11 = i01[2 * N_TOT + n * 2 + 1];
        val = w0 * Kn[c * N_TOT + c00] + w1 * Kn[c * N_TOT + c01]
            + w2 * G[c * N_TOT + c10]  + w3 * G[c * N_TOT + c11];
    }
    if (n == 0) {
        bool m0 = (flag[0] == 1.0f);
        int c00 = i01[0], c01 = i01[1];
        int c10 = i01[2 * N_TOT], c11 = i01[2 * N_TOT + 1];
        float kn0 = Kn[c * N_TOT];
        float g0  = G[c * N_TOT];
        if (!(m0 && c00 == 0)) val += w0 * kn0;
        if (!(m0 && c01 == 0)) val += w1 * kn0;
        if (!(m0 && c10 == 0)) val += w2 * g0;
        if (!(m0 && c11 == 0)) val += w3 * g0;
    }
    out[2 * C_DIM * N_TOT + c * N_TOT + n] = val;
}

// ---------------------------------------------------------------------------
extern "C" void kernel_launch(void* const* d_in, const int* in_sizes, int n_in,
                              void* d_out, int out_size, void* d_ws, size_t ws_size,
                              hipStream_t stream) {
    const float* G    = (const float*)d_in[0];   // generated, (C, N) row-major
    const float* Kn   = (const float*)d_in[1];   // known
    const float* flag = (const float*)d_in[2];   // mask, N floats of 0/1
    float* out = (float*)d_out;

    float* ws    = (float*)d_ws;
    float* cos0  = ws;                               // 1M floats
    float* cos1  = ws + N_TOT * N_TOT;               // 1M floats
    float* normP = ws + 2 * N_TOT * N_TOT;           // 1024
    float* normK = normP + N_TOT;                    // 1024
    float* w01   = normK + N_TOT;                    // 4096 floats [2][N][2]
    int*   i01   = (int*)(w01 + 4 * N_TOT);          // 4096 ints
    float* weights = (float*)(i01 + 4 * N_TOT);      // 4

    zero_kernel<<<1, 256, 0, stream>>>(normP);  // zeros normP+normK (2048 floats)
    norms_kernel<<<dim3(4, 32), 256, 0, stream>>>(G, Kn, normP, normK);
    gemm_cos<<<dim3(16, 16, 2), 256, 0, stream>>>(G, Kn, normP, normK, flag, cos0, cos1);
    topk_kernel<<<dim3(1024, 2), 64, 0, stream>>>(cos0, cos1, w01, i01);
    means_kernel<<<1, 256, 0, stream>>>(flag, w01, weights);
    output_kernel<<<dim3(4, 4096), 256, 0, stream>>>(G, Kn, flag, i01, weights, out);
}

// Round 2
// 204.797 us; speedup vs baseline: 2.0679x; 2.0679x over previous
//
#include <hip/hip_runtime.h>
#include <hip/hip_bf16.h>
#include <math.h>

#define N_TOT 1024
#define C_DIM 4096
#define NEGV  -1e30f

typedef __attribute__((ext_vector_type(8))) short short8;
typedef __attribute__((ext_vector_type(4))) float floatx4;

__device__ inline unsigned short bf16_rn(float v) {
    unsigned int u = __float_as_uint(v);
    unsigned int r = (u + 0x7FFFu + ((u >> 16) & 1u)) >> 16;
    return (unsigned short)r;
}

// ---------------------------------------------------------------------------
// split+transpose: X (C,N) fp32 -> Xhi[n][c], Xlo[n][c] bf16 (1024 x 4096).
// 64c x 64n tile per block. grid (64, 16, 2).
__global__ __launch_bounds__(256) void split_kernel(const float* __restrict__ G,
                                                    const float* __restrict__ Kn,
                                                    unsigned short* __restrict__ Phi,
                                                    unsigned short* __restrict__ Plo,
                                                    unsigned short* __restrict__ Khi,
                                                    unsigned short* __restrict__ Klo) {
    const int z = blockIdx.z;
    const float* X = z ? Kn : G;
    unsigned short* Xhi = z ? Khi : Phi;
    unsigned short* Xlo = z ? Klo : Plo;

    __shared__ float tile[64 * 65];
    const int t  = threadIdx.x;
    const int c0 = blockIdx.x * 64;
    const int n0 = blockIdx.y * 64;

    #pragma unroll
    for (int s = 0; s < 16; s++) {
        int c_loc = s * 4 + (t >> 6);
        int n_loc = t & 63;
        tile[c_loc * 65 + n_loc] = X[(c0 + c_loc) * N_TOT + n0 + n_loc];
    }
    __syncthreads();

    #pragma unroll
    for (int s = 0; s < 8; s++) {
        int n_loc = s * 8 + (t >> 5);
        int c2    = (t & 31) * 2;
        float v0 = tile[c2 * 65 + n_loc];
        float v1 = tile[(c2 + 1) * 65 + n_loc];
        unsigned short h0 = bf16_rn(v0);
        unsigned short h1 = bf16_rn(v1);
        float hf0 = __uint_as_float(((unsigned int)h0) << 16);
        float hf1 = __uint_as_float(((unsigned int)h1) << 16);
        unsigned short l0 = bf16_rn(v0 - hf0);
        unsigned short l1 = bf16_rn(v1 - hf1);
        size_t base = (size_t)(n0 + n_loc) * C_DIM + c0 + c2;
        *(ushort2*)&Xhi[base] = make_ushort2(h0, h1);
        *(ushort2*)&Xlo[base] = make_ushort2(l0, l1);
    }
}

// ---------------------------------------------------------------------------
__global__ __launch_bounds__(256) void zero_kernel(float* __restrict__ p) {
    int t = threadIdx.x;
    #pragma unroll
    for (int s = 0; s < 8; s++) p[t + s * 256] = 0.0f;
}

// ---------------------------------------------------------------------------
__global__ __launch_bounds__(256) void norms_kernel(const float* __restrict__ G,
                                                    const float* __restrict__ Kn,
                                                    float* __restrict__ normP,
                                                    float* __restrict__ normK) {
    int n  = blockIdx.x * 256 + threadIdx.x;
    int c0 = blockIdx.y * 128;
    float sp = 0.0f, sk = 0.0f;
    for (int c = c0; c < c0 + 128; c++) {
        float g = G[c * N_TOT + n];
        float k = Kn[c * N_TOT + n];
        sp = fmaf(g, g, sp);
        sk = fmaf(k, k, sk);
    }
    atomicAdd(&normP[n], sp);
    atomicAdd(&normK[n], sk);
}

// ---------------------------------------------------------------------------
// split-bf16 MFMA cosine GEMM. C[i][j] = sum_c A[i][c]*B[j][c]  (NT form).
// 64x64 tile / block, BK=64, 256 threads (4 waves, each 32x32).
// 3 MFMA products per tile pair: hh + hl + lh  (lo*lo dropped, ~1e-7 cos err).
// LDS staged via global_load_lds width=16, 16B-granule XOR swizzle for b128
// conflict-free fragment reads. grid (16,16,2): z=0 -> cos0(B=K), z=1 -> cos1.
__global__ __launch_bounds__(256) void gemm_mfma(const unsigned short* __restrict__ Phi,
                                                 const unsigned short* __restrict__ Plo,
                                                 const unsigned short* __restrict__ Khi,
                                                 const unsigned short* __restrict__ Klo,
                                                 const float* __restrict__ normP,
                                                 const float* __restrict__ normK,
                                                 const float* __restrict__ flag,
                                                 float* __restrict__ cos0,
                                                 float* __restrict__ cos1) {
    const int z = blockIdx.z;
    const unsigned short* Ahi = Phi;
    const unsigned short* Alo = Plo;
    const unsigned short* Bhi = z ? Phi : Khi;
    const unsigned short* Blo = z ? Plo : Klo;
    const float* nB = z ? normP : normK;
    float* out = z ? cos1 : cos0;

    __shared__ unsigned short sAhi[64 * 64];
    __shared__ unsigned short sAlo[64 * 64];
    __shared__ unsigned short sBhi[64 * 64];
    __shared__ unsigned short sBlo[64 * 64];

    const int t    = threadIdx.x;
    const int wave = t >> 6, lane = t & 63;
    const int wm   = wave >> 1, wn = wave & 1;
    const int quad = lane >> 4, lrow = lane & 15;
    const int ib = blockIdx.x * 64, jb = blockIdx.y * 64;

    // staging assignment: issue q in {0,1}: row = q*32 + (t>>3), granule g = (t&7)^(row&7)
    const int srow = t >> 3;            // 0..31
    const int g    = (t & 7) ^ (srow & 7);

    const unsigned short* gAhi = Ahi + (size_t)(ib + srow) * C_DIM + g * 8;
    const unsigned short* gAlo = Alo + (size_t)(ib + srow) * C_DIM + g * 8;
    const unsigned short* gBhi = Bhi + (size_t)(jb + srow) * C_DIM + g * 8;
    const unsigned short* gBlo = Blo + (size_t)(jb + srow) * C_DIM + g * 8;
    const size_t rstep = (size_t)32 * C_DIM;   // +32 rows for issue q=1

    floatx4 acc[2][2] = {};

    for (int k0 = 0; k0 < C_DIM; k0 += 64) {
        #pragma unroll
        for (int q = 0; q < 2; q++) {
            int lds_off = q * 4096 + t * 16;   // bytes
            __builtin_amdgcn_global_load_lds(
                (const __attribute__((address_space(1))) void*)(gAhi + q * rstep + k0),
                (__attribute__((address_space(3))) void*)((char*)sAhi + lds_off), 16, 0, 0);
            __builtin_amdgcn_global_load_lds(
                (const __attribute__((address_space(1))) void*)(gAlo + q * rstep + k0),
                (__attribute__((address_space(3))) void*)((char*)sAlo + lds_off), 16, 0, 0);
            __builtin_amdgcn_global_load_lds(
                (const __attribute__((address_space(1))) void*)(gBhi + q * rstep + k0),
                (__attribute__((address_space(3))) void*)((char*)sBhi + lds_off), 16, 0, 0);
            __builtin_amdgcn_global_load_lds(
                (const __attribute__((address_space(1))) void*)(gBlo + q * rstep + k0),
                (__attribute__((address_space(3))) void*)((char*)sBlo + lds_off), 16, 0, 0);
        }
        __syncthreads();

        #pragma unroll
        for (int kk = 0; kk < 2; kk++) {
            short8 a_hi[2], a_lo[2], b_hi[2], b_lo[2];
            #pragma unroll
            for (int ti = 0; ti < 2; ti++) {
                int m  = wm * 32 + ti * 16 + lrow;
                int gk = kk * 4 + quad;
                int off = m * 64 + ((gk ^ (m & 7)) << 3);
                a_hi[ti] = *(const short8*)&sAhi[off];
                a_lo[ti] = *(const short8*)&sAlo[off];
            }
            #pragma unroll
            for (int tj = 0; tj < 2; tj++) {
                int n  = wn * 32 + tj * 16 + lrow;
                int gk = kk * 4 + quad;
                int off = n * 64 + ((gk ^ (n & 7)) << 3);
                b_hi[tj] = *(const short8*)&sBhi[off];
                b_lo[tj] = *(const short8*)&sBlo[off];
            }
            #pragma unroll
            for (int ti = 0; ti < 2; ti++)
                #pragma unroll
                for (int tj = 0; tj < 2; tj++) {
                    acc[ti][tj] = __builtin_amdgcn_mfma_f32_16x16x32_bf16(a_hi[ti], b_hi[tj], acc[ti][tj], 0, 0, 0);
                    acc[ti][tj] = __builtin_amdgcn_mfma_f32_16x16x32_bf16(a_hi[ti], b_lo[tj], acc[ti][tj], 0, 0, 0);
                    acc[ti][tj] = __builtin_amdgcn_mfma_f32_16x16x32_bf16(a_lo[ti], b_hi[tj], acc[ti][tj], 0, 0, 0);
                }
        }
        __syncthreads();
    }

    // epilogue: normalize + column mask. C/D layout: col=lane&15, row=quad*4+reg.
    #pragma unroll
    for (int tj = 0; tj < 2; tj++) {
        int j = jb + wn * 32 + tj * 16 + lrow;
        float f = flag[j];
        bool keep = (f == (z ? 1.0f : 0.0f));
        float nb = nB[j];
        #pragma unroll
        for (int ti = 0; ti < 2; ti++) {
            #pragma unroll
            for (int reg = 0; reg < 4; reg++) {
                int i = ib + wm * 32 + ti * 16 + quad * 4 + reg;
                float v = acc[ti][tj][reg] * rsqrtf(normP[i] * nb);
                out[i * N_TOT + j] = keep ? v : NEGV;
            }
        }
    }
}

// ---------------------------------------------------------------------------
// per-row top-2 (values + global indices), tie-break lower index.
__global__ __launch_bounds__(64) void topk_kernel(const float* __restrict__ cos0,
                                                  const float* __restrict__ cos1,
                                                  float* __restrict__ w01,   // [2][N][2]
                                                  int* __restrict__ i01) {   // [2][N][2]
    const int row = blockIdx.x;
    const int z   = blockIdx.y;
    const float* M = z ? cos1 : cos0;
    const int lane = threadIdx.x;

    float v1 = -INFINITY, v2 = -INFINITY;
    int   j1 = -1, j2 = -1;

    for (int s = 0; s < 16; s++) {
        int j = s * 64 + lane;
        float v = M[row * N_TOT + j];
        if (v > v1 || (v == v1 && j < j1)) {
            v2 = v1; j2 = j1; v1 = v; j1 = j;
        } else if (v > v2 || (v == v2 && j < j2)) {
            v2 = v; j2 = j;
        }
    }

    for (int off = 32; off > 0; off >>= 1) {
        float ov1 = __shfl_down(v1, off);
        float ov2 = __shfl_down(v2, off);
        int   oj1 = __shfl_down(j1, off);
        int   oj2 = __shfl_down(j2, off);
        bool b1 = (ov1 > v1) || (ov1 == v1 && oj1 < j1);
        if (b1) {
            bool b2 = (v1 > ov2) || (v1 == ov2 && j1 < oj2);
            float nv2 = b2 ? v1 : ov2;
            int   nj2 = b2 ? j1 : oj2;
            v1 = ov1; j1 = oj1; v2 = nv2; j2 = nj2;
        } else {
            bool b2 = (ov1 > v2) || (ov1 == v2 && oj1 < j2);
            if (b2) { v2 = ov1; j2 = oj1; }
        }
    }

    if (lane == 0) {
        int base = (z * N_TOT + row) * 2;
        w01[base]     = v1;
        w01[base + 1] = v2;
        i01[base]     = j1;
        i01[base + 1] = j2;
    }
}

// ---------------------------------------------------------------------------
__global__ __launch_bounds__(256) void means_kernel(const float* __restrict__ flag,
                                                    const float* __restrict__ w01,
                                                    float* __restrict__ weights) {
    __shared__ float sd[5][256];
    const int t = threadIdx.x;
    float nm = 0.0f, s0 = 0.0f, s1 = 0.0f, s2 = 0.0f, s3 = 0.0f;
    for (int n = t; n < N_TOT; n += 256) {
        float m = flag[n];
        nm += m;
        s0 += m * w01[n * 2 + 0];
        s1 += m * w01[n * 2 + 1];
        s2 += m * w01[2 * N_TOT + n * 2 + 0];
        s3 += m * w01[2 * N_TOT + n * 2 + 1];
    }
    sd[0][t] = nm; sd[1][t] = s0; sd[2][t] = s1; sd[3][t] = s2; sd[4][t] = s3;
    __syncthreads();
    for (int off = 128; off > 0; off >>= 1) {
        if (t < off) {
            #pragma unroll
            for (int q = 0; q < 5; q++) sd[q][t] += sd[q][t + off];
        }
        __syncthreads();
    }
    if (t == 0) {
        float inv = 1.0f / sd[0][0];
        float mv[4] = {sd[1][0] * inv, sd[2][0] * inv, sd[3][0] * inv, sd[4][0] * inv};
        float mx = fmaxf(fmaxf(mv[0], mv[1]), fmaxf(mv[2], mv[3]));
        float e[4], tot = 0.0f;
        #pragma unroll
        for (int q = 0; q < 4; q++) { e[q] = expf(mv[q] - mx); tot += e[q]; }
        #pragma unroll
        for (int q = 0; q < 4; q++) weights[q] = e[q] / tot;
    }
}

// ---------------------------------------------------------------------------
__global__ __launch_bounds__(256) void output_kernel(const float* __restrict__ G,
                                                     const float* __restrict__ Kn,
                                                     const float* __restrict__ flag,
                                                     const int* __restrict__ i01,
                                                     const float* __restrict__ weights,
                                                     float* __restrict__ out) {
    const int n = blockIdx.x * 256 + threadIdx.x;
    const int c = blockIdx.y;

    float g = G[c * N_TOT + n];
    float k = Kn[c * N_TOT + n];
    out[c * N_TOT + n] = g;
    out[C_DIM * N_TOT + c * N_TOT + n] = k;

    const float w0 = weights[0], w1 = weights[1], w2 = weights[2], w3 = weights[3];

    float val = 0.0f;
    if (flag[n] == 1.0f) {
        int c00 = i01[n * 2 + 0];
        int c01 = i01[n * 2 + 1];
        int c10 = i01[2 * N_TOT + n * 2 + 0];
        int c11 = i01[2 * N_TOT + n * 2 + 1];
        val = w0 * Kn[c * N_TOT + c00] + w1 * Kn[c * N_TOT + c01]
            + w2 * G[c * N_TOT + c10]  + w3 * G[c * N_TOT + c11];
    }
    if (n == 0) {
        bool m0 = (flag[0] == 1.0f);
        int c00 = i01[0], c01 = i01[1];
        int c10 = i01[2 * N_TOT], c11 = i01[2 * N_TOT + 1];
        float kn0 = Kn[c * N_TOT];
        float g0  = G[c * N_TOT];
        if (!(m0 && c00 == 0)) val += w0 * kn0;
        if (!(m0 && c01 == 0)) val += w1 * kn0;
        if (!(m0 && c10 == 0)) val += w2 * g0;
        if (!(m0 && c11 == 0)) val += w3 * g0;
    }
    out[2 * C_DIM * N_TOT + c * N_TOT + n] = val;
}

// ---------------------------------------------------------------------------
extern "C" void kernel_launch(void* const* d_in, const int* in_sizes, int n_in,
                              void* d_out, int out_size, void* d_ws, size_t ws_size,
                              hipStream_t stream) {
    const float* G    = (const float*)d_in[0];
    const float* Kn   = (const float*)d_in[1];
    const float* flag = (const float*)d_in[2];
    float* out = (float*)d_out;

    // ws layout: split planes first (aligned), then cos, then small arrays.
    unsigned short* Phi = (unsigned short*)d_ws;                  // 8 MB each
    unsigned short* Plo = Phi + (size_t)N_TOT * C_DIM;
    unsigned short* Khi = Plo + (size_t)N_TOT * C_DIM;
    unsigned short* Klo = Khi + (size_t)N_TOT * C_DIM;
    float* cos0  = (float*)(Klo + (size_t)N_TOT * C_DIM);         // 4 MB
    float* cos1  = cos0 + (size_t)N_TOT * N_TOT;                  // 4 MB
    float* normP = cos1 + (size_t)N_TOT * N_TOT;
    float* normK = normP + N_TOT;
    float* w01   = normK + N_TOT;                                 // [2][N][2]
    int*   i01   = (int*)(w01 + 4 * N_TOT);
    float* weights = (float*)(i01 + 4 * N_TOT);

    split_kernel<<<dim3(64, 16, 2), 256, 0, stream>>>(G, Kn, Phi, Plo, Khi, Klo);
    zero_kernel<<<1, 256, 0, stream>>>(normP);
    norms_kernel<<<dim3(4, 32), 256, 0, stream>>>(G, Kn, normP, normK);
    gemm_mfma<<<dim3(16, 16, 2), 256, 0, stream>>>(Phi, Plo, Khi, Klo, normP, normK,
                                                   flag, cos0, cos1);
    topk_kernel<<<dim3(1024, 2), 64, 0, stream>>>(cos0, cos1, w01, i01);
    means_kernel<<<1, 256, 0, stream>>>(flag, w01, weights);
    output_kernel<<<dim3(4, 4096), 256, 0, stream>>>(G, Kn, flag, i01, weights, out);
}

// Round 3
// 188.247 us; speedup vs baseline: 2.2498x; 1.0879x over previous
//
#include <hip/hip_runtime.h>
#include <hip/hip_bf16.h>
#include <math.h>

#define N_TOT 1024
#define C_DIM 4096
#define NEGV  -1e30f

typedef __attribute__((ext_vector_type(8))) short short8;
typedef __attribute__((ext_vector_type(4))) float floatx4;

__device__ inline unsigned short bf16_rn(float v) {
    unsigned int u = __float_as_uint(v);
    unsigned int r = (u + 0x7FFFu + ((u >> 16) & 1u)) >> 16;
    return (unsigned short)r;
}

// ---------------------------------------------------------------------------
// split+transpose+norms: X (C,N) fp32 -> Xhi[n][c], Xlo[n][c] bf16, and
// normX[n] += sum_c x^2 (atomic, buffer pre-zeroed). grid (64, 16, 2).
__global__ __launch_bounds__(256) void split_norms(const float* __restrict__ G,
                                                   const float* __restrict__ Kn,
                                                   unsigned short* __restrict__ Phi,
                                                   unsigned short* __restrict__ Plo,
                                                   unsigned short* __restrict__ Khi,
                                                   unsigned short* __restrict__ Klo,
                                                   float* __restrict__ normP,
                                                   float* __restrict__ normK) {
    const int z = blockIdx.z;
    const float* X = z ? Kn : G;
    unsigned short* Xhi = z ? Khi : Phi;
    unsigned short* Xlo = z ? Klo : Plo;
    float* normX = z ? normK : normP;

    __shared__ float tile[64 * 65];
    __shared__ float np[256];
    const int t  = threadIdx.x;
    const int c0 = blockIdx.x * 64;
    const int n0 = blockIdx.y * 64;

    float s2 = 0.0f;
    #pragma unroll
    for (int s = 0; s < 16; s++) {
        int c_loc = s * 4 + (t >> 6);
        int n_loc = t & 63;
        float v = X[(c0 + c_loc) * N_TOT + n0 + n_loc];
        tile[c_loc * 65 + n_loc] = v;
        s2 = fmaf(v, v, s2);
    }
    np[t] = s2;
    __syncthreads();

    if (t < 64) {
        float tot = np[t] + np[t + 64] + np[t + 128] + np[t + 192];
        atomicAdd(&normX[n0 + t], tot);
    }

    #pragma unroll
    for (int s = 0; s < 8; s++) {
        int n_loc = s * 8 + (t >> 5);
        int c2    = (t & 31) * 2;
        float v0 = tile[c2 * 65 + n_loc];
        float v1 = tile[(c2 + 1) * 65 + n_loc];
        unsigned short h0 = bf16_rn(v0);
        unsigned short h1 = bf16_rn(v1);
        float hf0 = __uint_as_float(((unsigned int)h0) << 16);
        float hf1 = __uint_as_float(((unsigned int)h1) << 16);
        unsigned short l0 = bf16_rn(v0 - hf0);
        unsigned short l1 = bf16_rn(v1 - hf1);
        size_t base = (size_t)(n0 + n_loc) * C_DIM + c0 + c2;
        *(ushort2*)&Xhi[base] = make_ushort2(h0, h1);
        *(ushort2*)&Xlo[base] = make_ushort2(l0, l1);
    }
}

// ---------------------------------------------------------------------------
// fused split-bf16 MFMA GEMM: one block computes the 64x64 tile of BOTH
// dot0 = P.K^T and dot1 = P.P^T (A tile = P staged once, reused).
// grid (16,16,2): blockIdx.z = K-half (K=2048 each); raw dots accumulated
// with atomicAdd into pre-zeroed buffers. Normalization happens in topk.
// Per kk(K=32): 12 ds_read_b128 -> 24 MFMAs (ratio 2.0 vs 1.5 in R2).
__global__ __launch_bounds__(256) void gemm_fused(const unsigned short* __restrict__ Phi,
                                                  const unsigned short* __restrict__ Plo,
                                                  const unsigned short* __restrict__ Khi,
                                                  const unsigned short* __restrict__ Klo,
                                                  float* __restrict__ dot0,
                                                  float* __restrict__ dot1) {
    __shared__ unsigned short sAh[64 * 64];
    __shared__ unsigned short sAl[64 * 64];
    __shared__ unsigned short sKh[64 * 64];
    __shared__ unsigned short sKl[64 * 64];
    __shared__ unsigned short sPh[64 * 64];
    __shared__ unsigned short sPl[64 * 64];

    const int t    = threadIdx.x;
    const int wave = t >> 6, lane = t & 63;
    const int wm   = wave >> 1, wn = wave & 1;
    const int quad = lane >> 4, lrow = lane & 15;
    const int ib = blockIdx.x * 64, jb = blockIdx.y * 64;
    const int k_beg = blockIdx.z * 2048;

    const int srow = t >> 3;            // 0..31
    const int g    = (t & 7) ^ (srow & 7);

    const unsigned short* gAh = Phi + (size_t)(ib + srow) * C_DIM + g * 8;
    const unsigned short* gAl = Plo + (size_t)(ib + srow) * C_DIM + g * 8;
    const unsigned short* gKh = Khi + (size_t)(jb + srow) * C_DIM + g * 8;
    const unsigned short* gKl = Klo + (size_t)(jb + srow) * C_DIM + g * 8;
    const unsigned short* gPh = Phi + (size_t)(jb + srow) * C_DIM + g * 8;
    const unsigned short* gPl = Plo + (size_t)(jb + srow) * C_DIM + g * 8;
    const size_t rstep = (size_t)32 * C_DIM;

    floatx4 acc0[2][2] = {};
    floatx4 acc1[2][2] = {};

    for (int k0 = k_beg; k0 < k_beg + 2048; k0 += 64) {
        #pragma unroll
        for (int q = 0; q < 2; q++) {
            int lds_off = q * 4096 + t * 16;   // bytes
            #define STAGE(SPTR, GPTR) \
                __builtin_amdgcn_global_load_lds( \
                    (const __attribute__((address_space(1))) void*)((GPTR) + q * rstep + k0), \
                    (__attribute__((address_space(3))) void*)((char*)(SPTR) + lds_off), 16, 0, 0)
            STAGE(sAh, gAh); STAGE(sAl, gAl);
            STAGE(sKh, gKh); STAGE(sKl, gKl);
            STAGE(sPh, gPh); STAGE(sPl, gPl);
            #undef STAGE
        }
        __syncthreads();

        #pragma unroll
        for (int kk = 0; kk < 2; kk++) {
            short8 a_h[2], a_l[2], bk_h[2], bk_l[2], bp_h[2], bp_l[2];
            #pragma unroll
            for (int ti = 0; ti < 2; ti++) {
                int m  = wm * 32 + ti * 16 + lrow;
                int gk = kk * 4 + quad;
                int off = m * 64 + ((gk ^ (m & 7)) << 3);
                a_h[ti] = *(const short8*)&sAh[off];
                a_l[ti] = *(const short8*)&sAl[off];
            }
            #pragma unroll
            for (int tj = 0; tj < 2; tj++) {
                int n  = wn * 32 + tj * 16 + lrow;
                int gk = kk * 4 + quad;
                int off = n * 64 + ((gk ^ (n & 7)) << 3);
                bk_h[tj] = *(const short8*)&sKh[off];
                bk_l[tj] = *(const short8*)&sKl[off];
                bp_h[tj] = *(const short8*)&sPh[off];
                bp_l[tj] = *(const short8*)&sPl[off];
            }
            #pragma unroll
            for (int ti = 0; ti < 2; ti++)
                #pragma unroll
                for (int tj = 0; tj < 2; tj++) {
                    acc0[ti][tj] = __builtin_amdgcn_mfma_f32_16x16x32_bf16(a_h[ti], bk_h[tj], acc0[ti][tj], 0, 0, 0);
                    acc0[ti][tj] = __builtin_amdgcn_mfma_f32_16x16x32_bf16(a_h[ti], bk_l[tj], acc0[ti][tj], 0, 0, 0);
                    acc0[ti][tj] = __builtin_amdgcn_mfma_f32_16x16x32_bf16(a_l[ti], bk_h[tj], acc0[ti][tj], 0, 0, 0);
                    acc1[ti][tj] = __builtin_amdgcn_mfma_f32_16x16x32_bf16(a_h[ti], bp_h[tj], acc1[ti][tj], 0, 0, 0);
                    acc1[ti][tj] = __builtin_amdgcn_mfma_f32_16x16x32_bf16(a_h[ti], bp_l[tj], acc1[ti][tj], 0, 0, 0);
                    acc1[ti][tj] = __builtin_amdgcn_mfma_f32_16x16x32_bf16(a_l[ti], bp_h[tj], acc1[ti][tj], 0, 0, 0);
                }
        }
        __syncthreads();
    }

    // epilogue: accumulate raw dots. C/D layout: col=lane&15, row=quad*4+reg.
    #pragma unroll
    for (int tj = 0; tj < 2; tj++) {
        int j = jb + wn * 32 + tj * 16 + lrow;
        #pragma unroll
        for (int ti = 0; ti < 2; ti++) {
            #pragma unroll
            for (int reg = 0; reg < 4; reg++) {
                int i = ib + wm * 32 + ti * 16 + quad * 4 + reg;
                atomicAdd(&dot0[i * N_TOT + j], acc0[ti][tj][reg]);
                atomicAdd(&dot1[i * N_TOT + j], acc1[ti][tj][reg]);
            }
        }
    }
}

// ---------------------------------------------------------------------------
// per-row top-2 over cos = dot * rsqrt(normP[i]*normB[j]), columns masked by
// flag on the fly. tie-break lower index. grid (1024, 2), block 64.
__global__ __launch_bounds__(64) void topk_kernel(const float* __restrict__ dot0,
                                                  const float* __restrict__ dot1,
                                                  const float* __restrict__ normP,
                                                  const float* __restrict__ normK,
                                                  const float* __restrict__ flag,
                                                  float* __restrict__ w01,   // [2][N][2]
                                                  int* __restrict__ i01) {   // [2][N][2]
    const int row = blockIdx.x;
    const int z   = blockIdx.y;
    const float* D  = z ? dot1 : dot0;
    const float* nB = z ? normP : normK;
    const float target = z ? 1.0f : 0.0f;
    const int lane = threadIdx.x;
    const float nr = normP[row];

    float v1 = -INFINITY, v2 = -INFINITY;
    int   j1 = -1, j2 = -1;

    for (int s = 0; s < 16; s++) {
        int j = s * 64 + lane;
        float f = flag[j];
        float v = (f == target) ? D[row * N_TOT + j] * rsqrtf(nr * nB[j]) : NEGV;
        if (v > v1 || (v == v1 && j < j1)) {
            v2 = v1; j2 = j1; v1 = v; j1 = j;
        } else if (v > v2 || (v == v2 && j < j2)) {
            v2 = v; j2 = j;
        }
    }

    for (int off = 32; off > 0; off >>= 1) {
        float ov1 = __shfl_down(v1, off);
        float ov2 = __shfl_down(v2, off);
        int   oj1 = __shfl_down(j1, off);
        int   oj2 = __shfl_down(j2, off);
        bool b1 = (ov1 > v1) || (ov1 == v1 && oj1 < j1);
        if (b1) {
            bool b2 = (v1 > ov2) || (v1 == ov2 && j1 < oj2);
            float nv2 = b2 ? v1 : ov2;
            int   nj2 = b2 ? j1 : oj2;
            v1 = ov1; j1 = oj1; v2 = nv2; j2 = nj2;
        } else {
            bool b2 = (ov1 > v2) || (ov1 == v2 && oj1 < j2);
            if (b2) { v2 = ov1; j2 = oj1; }
        }
    }

    if (lane == 0) {
        int base = (z * N_TOT + row) * 2;
        w01[base]     = v1;
        w01[base + 1] = v2;
        i01[base]     = j1;
        i01[base + 1] = j2;
    }
}

// ---------------------------------------------------------------------------
__global__ __launch_bounds__(256) void means_kernel(const float* __restrict__ flag,
                                                    const float* __restrict__ w01,
                                                    float* __restrict__ weights) {
    __shared__ float sd[5][256];
    const int t = threadIdx.x;
    float nm = 0.0f, s0 = 0.0f, s1 = 0.0f, s2 = 0.0f, s3 = 0.0f;
    for (int n = t; n < N_TOT; n += 256) {
        float m = flag[n];
        nm += m;
        s0 += m * w01[n * 2 + 0];
        s1 += m * w01[n * 2 + 1];
        s2 += m * w01[2 * N_TOT + n * 2 + 0];
        s3 += m * w01[2 * N_TOT + n * 2 + 1];
    }
    sd[0][t] = nm; sd[1][t] = s0; sd[2][t] = s1; sd[3][t] = s2; sd[4][t] = s3;
    __syncthreads();
    for (int off = 128; off > 0; off >>= 1) {
        if (t < off) {
            #pragma unroll
            for (int q = 0; q < 5; q++) sd[q][t] += sd[q][t + off];
        }
        __syncthreads();
    }
    if (t == 0) {
        float inv = 1.0f / sd[0][0];
        float mv[4] = {sd[1][0] * inv, sd[2][0] * inv, sd[3][0] * inv, sd[4][0] * inv};
        float mx = fmaxf(fmaxf(mv[0], mv[1]), fmaxf(mv[2], mv[3]));
        float e[4], tot = 0.0f;
        #pragma unroll
        for (int q = 0; q < 4; q++) { e[q] = expf(mv[q] - mx); tot += e[q]; }
        #pragma unroll
        for (int q = 0; q < 4; q++) weights[q] = e[q] / tot;
    }
}

// ---------------------------------------------------------------------------
// output: copy generated & known (float4), rtn = sum_i w_i * gather_i.
// grid (4096), block 256: c = blockIdx.x, thread covers 4 consecutive n.
__global__ __launch_bounds__(256) void output_kernel(const float* __restrict__ G,
                                                     const float* __restrict__ Kn,
                                                     const float* __restrict__ flag,
                                                     const int* __restrict__ i01,
                                                     const float* __restrict__ weights,
                                                     float* __restrict__ out) {
    const int c  = blockIdx.x;
    const int n4 = threadIdx.x * 4;

    float4 gv = *(const float4*)&G[c * N_TOT + n4];
    float4 kv = *(const float4*)&Kn[c * N_TOT + n4];
    *(float4*)&out[c * N_TOT + n4] = gv;
    *(float4*)&out[C_DIM * N_TOT + c * N_TOT + n4] = kv;

    const float w0 = weights[0], w1 = weights[1], w2 = weights[2], w3 = weights[3];
    float4 fv = *(const float4*)&flag[n4];
    const float fa[4] = {fv.x, fv.y, fv.z, fv.w};

    float val[4];
    #pragma unroll
    for (int e = 0; e < 4; e++) {
        int n = n4 + e;
        float v = 0.0f;
        if (fa[e] == 1.0f) {
            int c00 = i01[n * 2 + 0];
            int c01 = i01[n * 2 + 1];
            int c10 = i01[2 * N_TOT + n * 2 + 0];
            int c11 = i01[2 * N_TOT + n * 2 + 1];
            v = w0 * Kn[c * N_TOT + c00] + w1 * Kn[c * N_TOT + c01]
              + w2 * G[c * N_TOT + c10]  + w3 * G[c * N_TOT + c11];
        }
        if (n == 0) {
            bool m0 = (flag[0] == 1.0f);
            int c00 = i01[0], c01 = i01[1];
            int c10 = i01[2 * N_TOT], c11 = i01[2 * N_TOT + 1];
            float kn0 = Kn[c * N_TOT];
            float g0  = G[c * N_TOT];
            if (!(m0 && c00 == 0)) v += w0 * kn0;
            if (!(m0 && c01 == 0)) v += w1 * kn0;
            if (!(m0 && c10 == 0)) v += w2 * g0;
            if (!(m0 && c11 == 0)) v += w3 * g0;
        }
        val[e] = v;
    }
    *(float4*)&out[2 * C_DIM * N_TOT + c * N_TOT + n4] =
        make_float4(val[0], val[1], val[2], val[3]);
}

// ---------------------------------------------------------------------------
extern "C" void kernel_launch(void* const* d_in, const int* in_sizes, int n_in,
                              void* d_out, int out_size, void* d_ws, size_t ws_size,
                              hipStream_t stream) {
    const float* G    = (const float*)d_in[0];
    const float* Kn   = (const float*)d_in[1];
    const float* flag = (const float*)d_in[2];
    float* out = (float*)d_out;

    // ws layout: bf16 planes (32 MB), then the atomically-accumulated f32
    // region (dot0, dot1, normP, normK -> zeroed by one memset), then small.
    unsigned short* Phi = (unsigned short*)d_ws;
    unsigned short* Plo = Phi + (size_t)N_TOT * C_DIM;
    unsigned short* Khi = Plo + (size_t)N_TOT * C_DIM;
    unsigned short* Klo = Khi + (size_t)N_TOT * C_DIM;
    float* dot0  = (float*)(Klo + (size_t)N_TOT * C_DIM);
    float* dot1  = dot0 + (size_t)N_TOT * N_TOT;
    float* normP = dot1 + (size_t)N_TOT * N_TOT;
    float* normK = normP + N_TOT;
    float* w01   = normK + N_TOT;                 // [2][N][2]
    int*   i01   = (int*)(w01 + 4 * N_TOT);
    float* weights = (float*)(i01 + 4 * N_TOT);

    const size_t zero_bytes = ((size_t)2 * N_TOT * N_TOT + 2 * N_TOT) * sizeof(float);
    hipMemsetAsync(dot0, 0, zero_bytes, stream);

    split_norms<<<dim3(64, 16, 2), 256, 0, stream>>>(G, Kn, Phi, Plo, Khi, Klo, normP, normK);
    gemm_fused<<<dim3(16, 16, 2), 256, 0, stream>>>(Phi, Plo, Khi, Klo, dot0, dot1);
    topk_kernel<<<dim3(1024, 2), 64, 0, stream>>>(dot0, dot1, normP, normK, flag, w01, i01);
    means_kernel<<<1, 256, 0, stream>>>(flag, w01, weights);
    output_kernel<<<4096, 256, 0, stream>>>(G, Kn, flag, i01, weights, out);
}